// Round 10
// baseline (77.068 us; speedup 1.0000x reference)
//
#include <hip/hip_runtime.h>
#include <stdint.h>

// RelationTransform: out[i] = W[relation[i]] @ node_emb[i]
// N=32768, EMB=512, 16 relations, fp32 in/out.
// Prepass (BW-bound, ~30us): histogram sort -> fused gather X->bf16 sorted Xs
// + zero pads + convert W->bf16 Ws.
// GEMM gg10: 256x256 tile, 512 thr (8 waves 2x4, 128x64 out/wave), 16 phases
// (K-slot=32): STAGE(slab t+2, ring-4) -> vmcnt(8) -> barrier -> 12x
// ds_read_b128 (XOR-swizzled) -> 32 MFMA (setprio). Counted vmcnt, no
// in-loop drain; LDS 128KB; tail drain 8->4->0.

#define EMB 512
#define N_RELC 16
#define BM 256
#define BN 256
#define KS 32          // K-slot per phase
#define NPH 16         // 512 / 32

typedef __attribute__((ext_vector_type(4))) float f32x4;
typedef __attribute__((ext_vector_type(8))) short bf16x8;

__device__ __forceinline__ unsigned short f2bf(float f) {
  unsigned int u = __float_as_uint(f);
  u += 0x7FFFu + ((u >> 16) & 1u);   // round-to-nearest-even
  return (unsigned short)(u >> 16);
}

__device__ __forceinline__ void gload_lds16(const void* g, void* l) {
  __builtin_amdgcn_global_load_lds(
      (const __attribute__((address_space(1))) unsigned int*)(uintptr_t)g,
      (__attribute__((address_space(3))) unsigned int*)(uintptr_t)l, 16, 0, 0);
}

// Per-block LDS histogram rank; also fills ptok[0..padn) with -1.
__global__ __launch_bounds__(256) void histo_rank_fill(
    const int* __restrict__ rel, int* cnt, int* pos, int* ptok,
    int n, int padn) {
  __shared__ int lcnt[N_RELC];
  __shared__ int lbase[N_RELC];
  const int tid = threadIdx.x;
  if (tid < N_RELC) lcnt[tid] = 0;
  __syncthreads();
  const int i = blockIdx.x * blockDim.x + tid;
  if (i < padn) ptok[i] = -1;
  int r = 0, myrank = 0;
  if (i < n) { r = rel[i]; myrank = atomicAdd(&lcnt[r], 1); }
  __syncthreads();
  if (tid < N_RELC) lbase[tid] = atomicAdd(&cnt[tid], lcnt[tid]);
  __syncthreads();
  if (i < n) pos[i] = lbase[r] + myrank;
}

// Padded (to BM=256) segment bases + tile table (1 block, 64 threads).
__global__ void prefix_tiles64(const int* __restrict__ cnt, int* pbase,
                               int* tinfo, int maxt) {
  __shared__ int sb[N_RELC + 1];
  __shared__ int st[N_RELC + 1];
  if (threadIdx.x == 0) {
    int acc = 0, t = 0;
    for (int r = 0; r < N_RELC; ++r) {
      sb[r] = acc; st[r] = t;
      const int nt = (cnt[r] + BM - 1) / BM;
      acc += nt * BM;
      t += nt;
    }
    sb[N_RELC] = acc; st[N_RELC] = t;
  }
  __syncthreads();
  for (int i = threadIdx.x; i <= N_RELC; i += blockDim.x) pbase[i] = sb[i];
  for (int x = threadIdx.x; x < maxt; x += blockDim.x) {
    int v = -1;
    #pragma unroll
    for (int r = 0; r < N_RELC; ++r)
      if (x >= st[r] && x < st[r + 1]) v = (r << 16) | (x - st[r]);
    tinfo[x] = v;
  }
}

// Fused prepass: blocks [0,gb) gather X->Xs (+ptok), [gb,gb+16) zero pads,
// rest convert W->Ws.
__global__ __launch_bounds__(256) void prep_all(
    const float* __restrict__ X, const float* __restrict__ W,
    const int* __restrict__ rel, const int* __restrict__ pos,
    const int* __restrict__ pbase, const int* __restrict__ cnt,
    unsigned short* __restrict__ Xs, unsigned short* __restrict__ Ws,
    int* __restrict__ ptok, int n, int welems, int gb)
{
  const int b = blockIdx.x;
  if (b < gb) {                       // ---- gather+convert 4 token rows ----
    const int row = b * 4 + (threadIdx.x >> 6);
    const int lane = threadIdx.x & 63;
    if (row >= n) return;
    const int dst = pbase[rel[row]] + pos[row];
    if (lane == 0) ptok[dst] = row;
    const float* src = X + (size_t)row * EMB + lane * 8;
    f32x4 a = *reinterpret_cast<const f32x4*>(src);
    f32x4 c = *reinterpret_cast<const f32x4*>(src + 4);
    bf16x8 o;
    o[0] = f2bf(a[0]); o[1] = f2bf(a[1]); o[2] = f2bf(a[2]); o[3] = f2bf(a[3]);
    o[4] = f2bf(c[0]); o[5] = f2bf(c[1]); o[6] = f2bf(c[2]); o[7] = f2bf(c[3]);
    *reinterpret_cast<bf16x8*>(Xs + (size_t)dst * EMB + lane * 8) = o;
  } else if (b < gb + N_RELC) {       // ---- zero pad rows of relation r ----
    const int r = b - gb;
    const int start = pbase[r] + cnt[r];
    const int end = pbase[r + 1];
    const int nvec = (end - start) * (EMB / 8);
    unsigned short* p = Xs + (size_t)start * EMB;
    const bf16x8 z = {0, 0, 0, 0, 0, 0, 0, 0};
    for (int v = threadIdx.x; v < nvec; v += blockDim.x)
      *reinterpret_cast<bf16x8*>(p + (size_t)v * 8) = z;
  } else {                            // ---- convert W -> bf16 ----
    const size_t i = (((size_t)(b - gb - N_RELC)) * 256 + threadIdx.x) * 8;
    if (i >= (size_t)welems) return;
    f32x4 a = *reinterpret_cast<const f32x4*>(W + i);
    f32x4 c = *reinterpret_cast<const f32x4*>(W + i + 4);
    bf16x8 o;
    o[0] = f2bf(a[0]); o[1] = f2bf(a[1]); o[2] = f2bf(a[2]); o[3] = f2bf(a[3]);
    o[4] = f2bf(c[0]); o[5] = f2bf(c[1]); o[6] = f2bf(c[2]); o[7] = f2bf(c[3]);
    *reinterpret_cast<bf16x8*>(Ws + i) = o;
  }
}

// ---------------------------------------------------------------------------
// gg10. LDS slabs: As/Bs[4][256 rows][32 bf16] (16KB each, 128KB total).
// Row = 64B = 4x16B granules; stored at phys granule g^( (row>>1)&3 )
// (inverse-applied on the global source column; forward on ds_read) ->
// fragment reads spread over 8 bank-quads (2-way = free).
// Phase t: STAGE slab (t+2)&3; vmcnt(8) [slab t retired]; barrier;
// read 4 B-frags + 8 A-frags (b128); 32 MFMA wrapped in setprio.
// Overwrite target's last readers were phase t-2 (>=2 barriers ago).
// ---------------------------------------------------------------------------

#define STAGE(S, T)                                                            \
  {                                                                            \
    const int kb_ = (T) * KS;                                                  \
    gload_lds16(a1 + kb_, (char*)&As[S][0] + tid * 16);                        \
    gload_lds16(a2 + kb_, (char*)&As[S][0] + 8192 + tid * 16);                 \
    gload_lds16(b1 + kb_, (char*)&Bs[S][0] + tid * 16);                        \
    gload_lds16(b2 + kb_, (char*)&Bs[S][0] + 8192 + tid * 16);                 \
  }

#define COMPUTE(S)                                                             \
  {                                                                            \
    bf16x8 bfr[4], af[8];                                                      \
    _Pragma("unroll")                                                          \
    for (int nn = 0; nn < 4; ++nn) {                                           \
      const int rw_ = wc * 64 + nn * 16 + lrow;                                \
      bfr[nn] = *reinterpret_cast<const bf16x8*>(                              \
          (const char*)&Bs[S][0] + rw_ * 64 + ((gl ^ ((rw_ >> 1) & 3)) * 16)); \
    }                                                                          \
    _Pragma("unroll")                                                          \
    for (int m = 0; m < 8; ++m) {                                              \
      const int rw_ = wr * 128 + m * 16 + lrow;                                \
      af[m] = *reinterpret_cast<const bf16x8*>(                                \
          (const char*)&As[S][0] + rw_ * 64 + ((gl ^ ((rw_ >> 1) & 3)) * 16)); \
    }                                                                          \
    __builtin_amdgcn_s_setprio(1);                                             \
    _Pragma("unroll")                                                          \
    for (int m = 0; m < 8; ++m)                                                \
      _Pragma("unroll")                                                        \
      for (int nn = 0; nn < 4; ++nn)                                           \
        acc[m][nn] = __builtin_amdgcn_mfma_f32_16x16x32_bf16(                  \
            af[m], bfr[nn], acc[m][nn], 0, 0, 0);                              \
    __builtin_amdgcn_s_setprio(0);                                             \
  }

#define ITER(T, VM)                                                            \
  {                                                                            \
    if ((T) + 2 < NPH) STAGE(((T) + 2) & 3, (T) + 2);                          \
    asm volatile("s_waitcnt vmcnt(" #VM ")" ::: "memory");                     \
    __builtin_amdgcn_s_barrier();                                              \
    __builtin_amdgcn_sched_barrier(0);                                         \
    COMPUTE((T) & 3);                                                          \
  }

__global__ __launch_bounds__(512, 2) void gg10(
    const unsigned short* __restrict__ Xs, const unsigned short* __restrict__ Ws,
    const int* __restrict__ pbase, const int* __restrict__ tinfo,
    const int* __restrict__ ptok, float* __restrict__ out)
{
  __shared__ unsigned short As[4][BM * KS];   // 4 x 16 KB
  __shared__ unsigned short Bs[4][BN * KS];   // 4 x 16 KB  (128 KB total)

  // Chunked bijective XCD swizzle (gridDim.x % 8 == 0): XCD c owns a
  // contiguous lid range; lid pairs (2k,2k+1) = same m-tile, ct 0/1.
  const int q = gridDim.x >> 3;
  const int lid = (blockIdx.x & 7) * q + (blockIdx.x >> 3);
  const int info = tinfo[lid >> 1];
  if (info < 0) return;
  const int r = info >> 16;
  const int mt = info & 0xFFFF;
  const int ct = lid & 1;
  const int prow0 = pbase[r] + mt * BM;

  const int tid = threadIdx.x;
  const int lane = tid & 63;
  const int wid = tid >> 6;
  const int wr = wid >> 2;          // 0..1 : 128-row band
  const int wc = wid & 3;           // 0..3 : 64-col band
  const int lrow = lane & 15;
  const int gl = lane >> 4;         // k-granule 0..3

  // Staging: chunk c=tid -> row tid>>2 (0..127); c=tid+512 -> row 128+.
  // Logical granule for phys (c&3): (c&3)^((c>>3)&3)  [same for both chunks
  // since (512>>3)&3 == 0].
  const int srow = tid >> 2;
  const int lg = (tid & 3) ^ ((tid >> 3) & 3);
  const unsigned short* a1 = Xs + (size_t)(prow0 + srow) * EMB + lg * 8;
  const unsigned short* a2 = a1 + (size_t)128 * EMB;
  const unsigned short* b1 =
      Ws + ((size_t)r * EMB + (size_t)(ct * BN + srow)) * EMB + lg * 8;
  const unsigned short* b2 = b1 + (size_t)128 * EMB;

  f32x4 acc[8][4];
  const f32x4 vzero = {0.f, 0.f, 0.f, 0.f};
  #pragma unroll
  for (int m = 0; m < 8; ++m)
    #pragma unroll
    for (int nn = 0; nn < 4; ++nn) acc[m][nn] = vzero;

  STAGE(0, 0);
  STAGE(1, 1);

  ITER(0, 8)   ITER(1, 8)   ITER(2, 8)   ITER(3, 8)
  ITER(4, 8)   ITER(5, 8)   ITER(6, 8)   ITER(7, 8)
  ITER(8, 8)   ITER(9, 8)   ITER(10, 8)  ITER(11, 8)
  ITER(12, 8)  ITER(13, 8)  ITER(14, 4)  ITER(15, 0)

  // Epilogue: D mapping col=lane&15, row=(lane>>4)*4+reg
  #pragma unroll
  for (int m = 0; m < 8; ++m) {
    const int base = prow0 + wr * 128 + m * 16 + gl * 4;
    #pragma unroll
    for (int rg = 0; rg < 4; ++rg) {
      const int tok = ptok[base + rg];
      if (tok >= 0) {
        float* orow = out + (size_t)tok * EMB + ct * BN + wc * 64;
        #pragma unroll
        for (int nn = 0; nn < 4; ++nn)
          orow[nn * 16 + lrow] = acc[m][nn][rg];
      }
    }
  }
}

// Safety-net naive kernel (only if ws too small).
__global__ void naive_kernel(const float* __restrict__ X, const int* __restrict__ rel,
                             const float* __restrict__ W, float* __restrict__ out, int n) {
  int i = blockIdx.x;
  if (i >= n) return;
  int r = rel[i];
  const float* x = X + (size_t)i * EMB;
  const float* Wr = W + (size_t)r * EMB * EMB;
  for (int j = threadIdx.x; j < EMB; j += blockDim.x) {
    const float* w = Wr + (size_t)j * EMB;
    float s = 0.f;
    for (int k = 0; k < EMB; ++k) s += w[k] * x[k];
    out[(size_t)i * EMB + j] = s;
  }
}

extern "C" void kernel_launch(void* const* d_in, const int* in_sizes, int n_in,
                              void* d_out, int out_size, void* d_ws, size_t ws_size,
                              hipStream_t stream) {
  const float* X  = (const float*)d_in[0];
  const int* rel  = (const int*)d_in[1];
  const float* W  = (const float*)d_in[2];
  float* out      = (float*)d_out;
  const int n = in_sizes[1];
  const int welems = in_sizes[2];                 // n_rel * EMB * EMB
  const int padn = n + N_RELC * BM;
  const int maxt = (n + BM - 1) / BM + N_RELC;
  const int maxtp = ((maxt + 3) / 4) * 4;         // grid = 2*maxtp, %8==0

  const size_t ints = (size_t)64 + n + padn + maxtp;
  const size_t offW = ((ints * sizeof(int) + 255) / 256) * 256;
  const size_t offX = offW + (((size_t)welems * 2 + 255) / 256) * 256;
  const size_t need = offX + (size_t)padn * EMB * 2;

  if (ws_size < need) {
    naive_kernel<<<n, 256, 0, stream>>>(X, rel, W, out, n);
    return;
  }

  int* cnt   = (int*)d_ws;       // 16 (+pad to 64)
  int* pbase = cnt + 16;         // 17
  int* pos   = cnt + 64;         // n
  int* ptok  = pos + n;          // padn
  int* tinfo = ptok + padn;      // maxtp
  unsigned short* Ws = (unsigned short*)((char*)d_ws + offW);
  unsigned short* Xs = (unsigned short*)((char*)d_ws + offX);

  const int gb = (n + 3) / 4;                       // gather blocks
  const int wb = (welems / 8 + 255) / 256;          // convert-W blocks

  hipMemsetAsync(cnt, 0, 64 * sizeof(int), stream);
  histo_rank_fill<<<(padn + 255) / 256, 256, 0, stream>>>(rel, cnt, pos, ptok, n, padn);
  prefix_tiles64<<<1, 64, 0, stream>>>(cnt, pbase, tinfo, maxtp);
  prep_all<<<gb + N_RELC + wb, 256, 0, stream>>>(X, W, rel, pos, pbase, cnt,
                                                 Xs, Ws, ptok, n, welems, gb);

  gg10<<<2 * maxtp, 512, 0, stream>>>(Xs, Ws, pbase, tinfo, ptok, out);
}

// Round 11
// 71.577 us; speedup vs baseline: 1.0767x; 1.0767x over previous
//
#include <hip/hip_runtime.h>
#include <stdint.h>

// RelationTransform: out[i] = W[relation[i]] @ node_emb[i]
// N=32768, EMB=512, 16 relations, fp32 in/out.
// Prepass (cheap, ~7us): histogram sort (ptok) + W->bf16 convert (24MB).
// GEMM gg11: A staged fp32 DIRECT from X (per-lane ptok gather via
// global_load_lds), B bf16 from Ws. 128x128 tile, 256 thr, 1088 blocks,
// ring-3 slabs (72KB -> 2 blocks/CU), counted vmcnt(12) never drained
// in-loop, conflict-free XOR swizzles both operands (gg10-verified),
// ct-fastest + chunked XCD swizzle for X L2 reuse.

#define EMB 512
#define N_RELC 16
#define BM 128
#define BN 128
#define BK 32
#define NKT 16

typedef __attribute__((ext_vector_type(4))) float f32x4;
typedef __attribute__((ext_vector_type(8))) short bf16x8;

__device__ __forceinline__ unsigned short f2bf(float f) {
  unsigned int u = __float_as_uint(f);
  u += 0x7FFFu + ((u >> 16) & 1u);   // round-to-nearest-even
  return (unsigned short)(u >> 16);
}

__device__ __forceinline__ bf16x8 cvt8(f32x4 lo, f32x4 hi) {
  bf16x8 o;
  o[0] = (short)f2bf(lo[0]); o[1] = (short)f2bf(lo[1]);
  o[2] = (short)f2bf(lo[2]); o[3] = (short)f2bf(lo[3]);
  o[4] = (short)f2bf(hi[0]); o[5] = (short)f2bf(hi[1]);
  o[6] = (short)f2bf(hi[2]); o[7] = (short)f2bf(hi[3]);
  return o;
}

__device__ __forceinline__ void gload_lds16(const void* g, void* l) {
  __builtin_amdgcn_global_load_lds(
      (const __attribute__((address_space(1))) unsigned int*)(uintptr_t)g,
      (__attribute__((address_space(3))) unsigned int*)(uintptr_t)l, 16, 0, 0);
}

// Per-block LDS histogram rank; also fills ptok[0..padn) with -1.
__global__ __launch_bounds__(256) void histo_rank_fill(
    const int* __restrict__ rel, int* cnt, int* pos, int* ptok,
    int n, int padn) {
  __shared__ int lcnt[N_RELC];
  __shared__ int lbase[N_RELC];
  const int tid = threadIdx.x;
  if (tid < N_RELC) lcnt[tid] = 0;
  __syncthreads();
  const int i = blockIdx.x * blockDim.x + tid;
  if (i < padn) ptok[i] = -1;
  int r = 0, myrank = 0;
  if (i < n) { r = rel[i]; myrank = atomicAdd(&lcnt[r], 1); }
  __syncthreads();
  if (tid < N_RELC) lbase[tid] = atomicAdd(&cnt[tid], lcnt[tid]);
  __syncthreads();
  if (i < n) pos[i] = lbase[r] + myrank;
}

// Padded segment bases + tile table (1 block, 64 threads).
__global__ void prefix_tiles64(const int* __restrict__ cnt, int* pbase,
                               int* tinfo, int maxt) {
  __shared__ int sb[N_RELC + 1];
  __shared__ int st[N_RELC + 1];
  if (threadIdx.x == 0) {
    int acc = 0, t = 0;
    for (int r = 0; r < N_RELC; ++r) {
      sb[r] = acc; st[r] = t;
      const int nt = (cnt[r] + BM - 1) / BM;
      acc += nt * BM;
      t += nt;
    }
    sb[N_RELC] = acc; st[N_RELC] = t;
  }
  __syncthreads();
  for (int i = threadIdx.x; i <= N_RELC; i += blockDim.x) pbase[i] = sb[i];
  for (int x = threadIdx.x; x < maxt; x += blockDim.x) {
    int v = -1;
    #pragma unroll
    for (int r = 0; r < N_RELC; ++r)
      if (x >= st[r] && x < st[r + 1]) v = (r << 16) | (x - st[r]);
    tinfo[x] = v;
  }
}

__global__ __launch_bounds__(256) void scatter_ptok(
    const int* __restrict__ rel, const int* __restrict__ pos,
    const int* __restrict__ pbase, int* __restrict__ ptok, int n) {
  const int i = blockIdx.x * blockDim.x + threadIdx.x;
  if (i < n) ptok[pbase[rel[i]] + pos[i]] = i;
}

__global__ __launch_bounds__(256) void convert_W(const float* __restrict__ W,
                                                 unsigned short* __restrict__ Ws,
                                                 int welems) {
  const size_t i = ((size_t)blockIdx.x * 256 + threadIdx.x) * 8;
  if (i >= (size_t)welems) return;
  f32x4 a = *reinterpret_cast<const f32x4*>(W + i);
  f32x4 c = *reinterpret_cast<const f32x4*>(W + i + 4);
  bf16x8 o;
  o[0] = f2bf(a[0]); o[1] = f2bf(a[1]); o[2] = f2bf(a[2]); o[3] = f2bf(a[3]);
  o[4] = f2bf(c[0]); o[5] = f2bf(c[1]); o[6] = f2bf(c[2]); o[7] = f2bf(c[3]);
  *reinterpret_cast<bf16x8*>(Ws + i) = o;
}

// ---------------------------------------------------------------------------
// gg11. LDS: As[3] fp32 [128][32] (16KB, 128B rows = 8 slots, phys slot =
// log ^ (row&7)); Bs[3] bf16 [128][32] (8KB, 64B rows = 4 granules, phys =
// log ^ ((row>>1)&3), gg10-verified 0-conflict). Inverse swizzle on the
// per-lane GLOBAL source column (gload_lds dest is linear base+lane*16).
// ITER(t): STAGE slab (t+2)%3 [6 loads] -> vmcnt(12) [slab t landed] ->
// barrier -> COMPUTE(t%3) [8 A-reads+cvt, 4 B-reads, 16 MFMA] -> lgkm(0)
// -> barrier. Tail 12 -> 6 -> 0.
// ---------------------------------------------------------------------------

#define STAGE(S, KT)                                                           \
  {                                                                            \
    const int kb_ = (KT) * BK;                                                 \
    gload_lds16(asrc0 + kb_, (char*)&As[S][0] + tid * 16);                     \
    gload_lds16(asrc1 + kb_, (char*)&As[S][0] + 4096 + tid * 16);              \
    gload_lds16(asrc2 + kb_, (char*)&As[S][0] + 8192 + tid * 16);              \
    gload_lds16(asrc3 + kb_, (char*)&As[S][0] + 12288 + tid * 16);             \
    gload_lds16(bsrc0 + kb_, (char*)&Bs[S][0] + tid * 16);                     \
    gload_lds16(bsrc1 + kb_, (char*)&Bs[S][0] + 4096 + tid * 16);              \
  }

#define COMPUTE(S)                                                             \
  {                                                                            \
    bf16x8 af[4], bfr[4];                                                      \
    _Pragma("unroll")                                                          \
    for (int m = 0; m < 4; ++m) {                                              \
      const int rr_ = wr * 64 + m * 16 + lrow;                                 \
      const char* base_ = (const char*)&As[S][0] + rr_ * 128;                  \
      f32x4 lo = *reinterpret_cast<const f32x4*>(                              \
          base_ + (((gl * 2) ^ (rr_ & 7)) * 16));                              \
      f32x4 hi = *reinterpret_cast<const f32x4*>(                              \
          base_ + (((gl * 2 + 1) ^ (rr_ & 7)) * 16));                          \
      af[m] = cvt8(lo, hi);                                                    \
    }                                                                          \
    _Pragma("unroll")                                                          \
    for (int nn = 0; nn < 4; ++nn) {                                           \
      const int rw_ = wc * 64 + nn * 16 + lrow;                                \
      bfr[nn] = *reinterpret_cast<const bf16x8*>(                              \
          (const char*)&Bs[S][0] + rw_ * 64 + ((gl ^ ((rw_ >> 1) & 3)) * 16)); \
    }                                                                          \
    _Pragma("unroll")                                                          \
    for (int m = 0; m < 4; ++m)                                                \
      _Pragma("unroll")                                                        \
      for (int nn = 0; nn < 4; ++nn)                                           \
        acc[m][nn] = __builtin_amdgcn_mfma_f32_16x16x32_bf16(                  \
            af[m], bfr[nn], acc[m][nn], 0, 0, 0);                              \
  }

#define ITER(T, VM)                                                            \
  {                                                                            \
    if ((T) + 2 < NKT) STAGE(((T) + 2) % 3, (T) + 2);                          \
    asm volatile("s_waitcnt vmcnt(" #VM ")" ::: "memory");                     \
    __builtin_amdgcn_s_barrier();                                              \
    __builtin_amdgcn_sched_barrier(0);                                         \
    COMPUTE((T) % 3);                                                          \
    asm volatile("s_waitcnt lgkmcnt(0)" ::: "memory");                         \
    __builtin_amdgcn_s_barrier();                                              \
    __builtin_amdgcn_sched_barrier(0);                                         \
  }

__global__ __launch_bounds__(256, 2) void gg11(
    const float* __restrict__ X, const unsigned short* __restrict__ Ws,
    const int* __restrict__ pbase, const int* __restrict__ tinfo,
    const int* __restrict__ ptok, float* __restrict__ out)
{
  __shared__ float As[3][BM * BK];            // 3 x 16 KB
  __shared__ unsigned short Bs[3][BN * BK];   // 3 x 8 KB   (72 KB total)

  // Chunked bijective XCD swizzle (gridDim.x % 8 == 0). lid: ct fastest ->
  // the 4 ct-siblings of an m-tile are contiguous -> same XCD chunk -> the
  // X rows they gather are fetched once per XCD and L2-served 3x.
  const int q = gridDim.x >> 3;
  const int lid = ((int)blockIdx.x & 7) * q + ((int)blockIdx.x >> 3);
  const int info = tinfo[lid >> 2];
  if (info < 0) return;
  const int r = info >> 16;
  const int mt = info & 0xFFFF;
  const int ct = lid & 3;
  const int prow0 = pbase[r] + mt * BM;

  const int tid = threadIdx.x;
  const int lane = tid & 63;
  const int wid = tid >> 6;
  const int wr = wid >> 1, wc = wid & 1;
  const int lrow = lane & 15;
  const int gl = lane >> 4;

  // A staging (fp32 gather): shot s covers row s*32 + (tid>>3); phys slot
  // (tid&7) holds logical slot (tid&7)^(row&7) -> swizzle the source col.
  const int arow = tid >> 3;
  const int aslot = (tid & 7) ^ (arow & 7);
  int t0 = ptok[prow0 + arow];        if (t0 < 0) t0 = 0;
  int t1 = ptok[prow0 + 32 + arow];   if (t1 < 0) t1 = 0;
  int t2 = ptok[prow0 + 64 + arow];   if (t2 < 0) t2 = 0;
  int t3 = ptok[prow0 + 96 + arow];   if (t3 < 0) t3 = 0;
  const float* asrc0 = X + (size_t)t0 * EMB + aslot * 4;
  const float* asrc1 = X + (size_t)t1 * EMB + aslot * 4;
  const float* asrc2 = X + (size_t)t2 * EMB + aslot * 4;
  const float* asrc3 = X + (size_t)t3 * EMB + aslot * 4;
  // B staging (bf16): shot s covers row s*64 + (tid>>2); phys granule
  // (tid&3) holds logical (tid&3)^((row>>1)&3) = (tid&3)^((tid>>3)&3).
  const int brow = tid >> 2;
  const int bgran = (tid & 3) ^ ((tid >> 3) & 3);
  const unsigned short* bsrc0 =
      Ws + ((size_t)r * EMB + (size_t)(ct * BN + brow)) * EMB + bgran * 8;
  const unsigned short* bsrc1 = bsrc0 + (size_t)64 * EMB;

  f32x4 acc[4][4];
  const f32x4 vzero = {0.f, 0.f, 0.f, 0.f};
  #pragma unroll
  for (int m = 0; m < 4; ++m)
    #pragma unroll
    for (int nn = 0; nn < 4; ++nn) acc[m][nn] = vzero;

  STAGE(0, 0);
  STAGE(1, 1);

  ITER(0, 12)  ITER(1, 12)  ITER(2, 12)  ITER(3, 12)
  ITER(4, 12)  ITER(5, 12)  ITER(6, 12)  ITER(7, 12)
  ITER(8, 12)  ITER(9, 12)  ITER(10, 12) ITER(11, 12)
  ITER(12, 12) ITER(13, 12) ITER(14, 6)  ITER(15, 0)

  // Epilogue: D mapping col=lane&15, row=(lane>>4)*4+reg
  #pragma unroll
  for (int m = 0; m < 4; ++m) {
    const int base = prow0 + wr * 64 + m * 16 + gl * 4;
    #pragma unroll
    for (int rg = 0; rg < 4; ++rg) {
      const int tok = ptok[base + rg];
      if (tok >= 0) {
        float* orow = out + (size_t)tok * EMB + ct * BN + wc * 64;
        #pragma unroll
        for (int nn = 0; nn < 4; ++nn)
          orow[nn * 16 + lrow] = acc[m][nn][rg];
      }
    }
  }
}

// Safety-net naive kernel (only if ws too small).
__global__ void naive_kernel(const float* __restrict__ X, const int* __restrict__ rel,
                             const float* __restrict__ W, float* __restrict__ out, int n) {
  int i = blockIdx.x;
  if (i >= n) return;
  int r = rel[i];
  const float* x = X + (size_t)i * EMB;
  const float* Wr = W + (size_t)r * EMB * EMB;
  for (int j = threadIdx.x; j < EMB; j += blockDim.x) {
    const float* w = Wr + (size_t)j * EMB;
    float s = 0.f;
    for (int k = 0; k < EMB; ++k) s += w[k] * x[k];
    out[(size_t)i * EMB + j] = s;
  }
}

extern "C" void kernel_launch(void* const* d_in, const int* in_sizes, int n_in,
                              void* d_out, int out_size, void* d_ws, size_t ws_size,
                              hipStream_t stream) {
  const float* X  = (const float*)d_in[0];
  const int* rel  = (const int*)d_in[1];
  const float* W  = (const float*)d_in[2];
  float* out      = (float*)d_out;
  const int n = in_sizes[1];
  const int welems = in_sizes[2];                 // n_rel * EMB * EMB
  const int padn = n + N_RELC * BM;
  const int maxt = (n + BM - 1) / BM + N_RELC;
  const int maxtp = ((maxt + 1) / 2) * 2;         // grid = 4*maxtp -> %8==0

  const size_t ints = (size_t)64 + n + padn + maxtp;
  const size_t offW = ((ints * sizeof(int) + 255) / 256) * 256;
  const size_t need = offW + (size_t)welems * 2;

  if (ws_size < need) {
    naive_kernel<<<n, 256, 0, stream>>>(X, rel, W, out, n);
    return;
  }

  int* cnt   = (int*)d_ws;       // 16 (+pad to 64)
  int* pbase = cnt + 16;         // 17
  int* pos   = cnt + 64;         // n
  int* ptok  = pos + n;          // padn
  int* tinfo = ptok + padn;      // maxtp
  unsigned short* Ws = (unsigned short*)((char*)d_ws + offW);

  hipMemsetAsync(cnt, 0, 64 * sizeof(int), stream);
  histo_rank_fill<<<(padn + 255) / 256, 256, 0, stream>>>(rel, cnt, pos, ptok, n, padn);
  prefix_tiles64<<<1, 64, 0, stream>>>(cnt, pbase, tinfo, maxtp);
  scatter_ptok<<<(n + 255) / 256, 256, 0, stream>>>(rel, pos, pbase, ptok, n);
  convert_W<<<(welems / 8 + 255) / 256, 256, 0, stream>>>(W, Ws, welems);

  gg11<<<4 * maxtp, 256, 0, stream>>>(X, Ws, pbase, tinfo, ptok, out);
}

// Round 12
// 70.685 us; speedup vs baseline: 1.0903x; 1.0126x over previous
//
#include <hip/hip_runtime.h>
#include <stdint.h>

// RelationTransform: out[i] = W[relation[i]] @ node_emb[i]
// N=32768, EMB=512, 16 relations, fp32 in/out.
// Prepass: histogram sort -> fused (gather X->bf16 sorted Xs + zero pads +
// convert W->bf16 Ws).
// GEMM gg12: bf16 prestaged both sides (fast core), 128x256 tile, 512 thr
// (8 waves 2x4, 64x64 out/wave), BK=32, ring-3 slabs (72KB -> 2 blocks/CU),
// counted vmcnt(6) never drained in-loop, gg10-verified granule swizzle
// (0 bank conflicts), chunked bijective XCD swizzle with ct-minor lids so
// each XCD chunk holds whole m-tile groups -> Xs/W staged from its OWN L2.

#define EMB 512
#define N_RELC 16
#define BM 128
#define BN 256
#define BK 32
#define NKT 16

typedef __attribute__((ext_vector_type(4))) float f32x4;
typedef __attribute__((ext_vector_type(8))) short bf16x8;

__device__ __forceinline__ unsigned short f2bf(float f) {
  unsigned int u = __float_as_uint(f);
  u += 0x7FFFu + ((u >> 16) & 1u);   // round-to-nearest-even
  return (unsigned short)(u >> 16);
}

__device__ __forceinline__ void gload_lds16(const void* g, void* l) {
  __builtin_amdgcn_global_load_lds(
      (const __attribute__((address_space(1))) unsigned int*)(uintptr_t)g,
      (__attribute__((address_space(3))) unsigned int*)(uintptr_t)l, 16, 0, 0);
}

// Per-block LDS histogram rank; also fills ptok[0..padn) with -1.
__global__ __launch_bounds__(256) void histo_rank_fill(
    const int* __restrict__ rel, int* cnt, int* pos, int* ptok,
    int n, int padn) {
  __shared__ int lcnt[N_RELC];
  __shared__ int lbase[N_RELC];
  const int tid = threadIdx.x;
  if (tid < N_RELC) lcnt[tid] = 0;
  __syncthreads();
  const int i = blockIdx.x * blockDim.x + tid;
  if (i < padn) ptok[i] = -1;
  int r = 0, myrank = 0;
  if (i < n) { r = rel[i]; myrank = atomicAdd(&lcnt[r], 1); }
  __syncthreads();
  if (tid < N_RELC) lbase[tid] = atomicAdd(&cnt[tid], lcnt[tid]);
  __syncthreads();
  if (i < n) pos[i] = lbase[r] + myrank;
}

// Padded segment bases + tile table (1 block, 64 threads).
__global__ void prefix_tiles64(const int* __restrict__ cnt, int* pbase,
                               int* tinfo, int maxt) {
  __shared__ int sb[N_RELC + 1];
  __shared__ int st[N_RELC + 1];
  if (threadIdx.x == 0) {
    int acc = 0, t = 0;
    for (int r = 0; r < N_RELC; ++r) {
      sb[r] = acc; st[r] = t;
      const int nt = (cnt[r] + BM - 1) / BM;
      acc += nt * BM;
      t += nt;
    }
    sb[N_RELC] = acc; st[N_RELC] = t;
  }
  __syncthreads();
  for (int i = threadIdx.x; i <= N_RELC; i += blockDim.x) pbase[i] = sb[i];
  for (int x = threadIdx.x; x < maxt; x += blockDim.x) {
    int v = -1;
    #pragma unroll
    for (int r = 0; r < N_RELC; ++r)
      if (x >= st[r] && x < st[r + 1]) v = (r << 16) | (x - st[r]);
    tinfo[x] = v;
  }
}

// Fused prepass: blocks [0,gb) gather X->Xs (+ptok), [gb,gb+16) zero pads,
// rest convert W->Ws.
__global__ __launch_bounds__(256) void prep_all(
    const float* __restrict__ X, const float* __restrict__ W,
    const int* __restrict__ rel, const int* __restrict__ pos,
    const int* __restrict__ pbase, const int* __restrict__ cnt,
    unsigned short* __restrict__ Xs, unsigned short* __restrict__ Ws,
    int* __restrict__ ptok, int n, int welems, int gb)
{
  const int b = blockIdx.x;
  if (b < gb) {                       // ---- gather+convert 4 token rows ----
    const int row = b * 4 + (threadIdx.x >> 6);
    const int lane = threadIdx.x & 63;
    if (row >= n) return;
    const int dst = pbase[rel[row]] + pos[row];
    if (lane == 0) ptok[dst] = row;
    const float* src = X + (size_t)row * EMB + lane * 8;
    f32x4 a = *reinterpret_cast<const f32x4*>(src);
    f32x4 c = *reinterpret_cast<const f32x4*>(src + 4);
    bf16x8 o;
    o[0] = f2bf(a[0]); o[1] = f2bf(a[1]); o[2] = f2bf(a[2]); o[3] = f2bf(a[3]);
    o[4] = f2bf(c[0]); o[5] = f2bf(c[1]); o[6] = f2bf(c[2]); o[7] = f2bf(c[3]);
    *reinterpret_cast<bf16x8*>(Xs + (size_t)dst * EMB + lane * 8) = o;
  } else if (b < gb + N_RELC) {       // ---- zero pad rows of relation r ----
    const int r = b - gb;
    const int start = pbase[r] + cnt[r];
    const int end = pbase[r + 1];
    const int nvec = (end - start) * (EMB / 8);
    unsigned short* p = Xs + (size_t)start * EMB;
    const bf16x8 z = {0, 0, 0, 0, 0, 0, 0, 0};
    for (int v = threadIdx.x; v < nvec; v += blockDim.x)
      *reinterpret_cast<bf16x8*>(p + (size_t)v * 8) = z;
  } else {                            // ---- convert W -> bf16 ----
    const size_t i = (((size_t)(b - gb - N_RELC)) * 256 + threadIdx.x) * 8;
    if (i >= (size_t)welems) return;
    f32x4 a = *reinterpret_cast<const f32x4*>(W + i);
    f32x4 c = *reinterpret_cast<const f32x4*>(W + i + 4);
    bf16x8 o;
    o[0] = f2bf(a[0]); o[1] = f2bf(a[1]); o[2] = f2bf(a[2]); o[3] = f2bf(a[3]);
    o[4] = f2bf(c[0]); o[5] = f2bf(c[1]); o[6] = f2bf(c[2]); o[7] = f2bf(c[3]);
    *reinterpret_cast<bf16x8*>(Ws + i) = o;
  }
}

// ---------------------------------------------------------------------------
// gg12. LDS slabs (ring-3): As [128][32] bf16 = 8KB, Bs [256][32] bf16 =
// 16KB. 64B rows = 4 x 16B granules, phys granule = log ^ ((row>>1)&3)
// (gg10-verified 0-conflict); inverse applied on the global source column.
// ITER(t): STAGE slab (t+2)%3 [3 gload_lds] -> vmcnt(6) [slab t landed] ->
// barrier -> COMPUTE(t%3) [4 A-frags, 4 B-frags, 16 MFMA in setprio] ->
// lgkm(0) -> barrier. Tail 6 -> 3 -> 0.
// ---------------------------------------------------------------------------

#define STAGE(S, KT)                                                           \
  {                                                                            \
    const int kb_ = (KT) * BK;                                                 \
    gload_lds16(asrc + kb_, (char*)&As[S][0] + tid * 16);                      \
    gload_lds16(bsrc0 + kb_, (char*)&Bs[S][0] + tid * 16);                     \
    gload_lds16(bsrc1 + kb_, (char*)&Bs[S][0] + 8192 + tid * 16);              \
  }

#define COMPUTE(S)                                                             \
  {                                                                            \
    bf16x8 af[4], bfr[4];                                                      \
    _Pragma("unroll")                                                          \
    for (int m = 0; m < 4; ++m) {                                              \
      const int rr_ = wr * 64 + m * 16 + lrow;                                 \
      af[m] = *reinterpret_cast<const bf16x8*>(                                \
          (const char*)&As[S][0] + rr_ * 64 + ((gl ^ ((rr_ >> 1) & 3)) * 16)); \
    }                                                                          \
    _Pragma("unroll")                                                          \
    for (int nn = 0; nn < 4; ++nn) {                                           \
      const int rw_ = wc * 64 + nn * 16 + lrow;                                \
      bfr[nn] = *reinterpret_cast<const bf16x8*>(                              \
          (const char*)&Bs[S][0] + rw_ * 64 + ((gl ^ ((rw_ >> 1) & 3)) * 16)); \
    }                                                                          \
    __builtin_amdgcn_s_setprio(1);                                             \
    _Pragma("unroll")                                                          \
    for (int m = 0; m < 4; ++m)                                                \
      _Pragma("unroll")                                                        \
      for (int nn = 0; nn < 4; ++nn)                                           \
        acc[m][nn] = __builtin_amdgcn_mfma_f32_16x16x32_bf16(                  \
            af[m], bfr[nn], acc[m][nn], 0, 0, 0);                              \
    __builtin_amdgcn_s_setprio(0);                                             \
  }

#define ITER(T, VM)                                                            \
  {                                                                            \
    if ((T) + 2 < NKT) STAGE(((T) + 2) % 3, (T) + 2);                          \
    asm volatile("s_waitcnt vmcnt(" #VM ")" ::: "memory");                     \
    __builtin_amdgcn_s_barrier();                                              \
    __builtin_amdgcn_sched_barrier(0);                                         \
    COMPUTE((T) % 3);                                                          \
    asm volatile("s_waitcnt lgkmcnt(0)" ::: "memory");                         \
    __builtin_amdgcn_s_barrier();                                              \
    __builtin_amdgcn_sched_barrier(0);                                         \
  }

__global__ __launch_bounds__(512, 4) void gg12(
    const unsigned short* __restrict__ Xs, const unsigned short* __restrict__ Ws,
    const int* __restrict__ pbase, const int* __restrict__ tinfo,
    const int* __restrict__ ptok, float* __restrict__ out)
{
  __shared__ unsigned short As[3][BM * BK];   // 3 x 8 KB
  __shared__ unsigned short Bs[3][BN * BK];   // 3 x 16 KB  (72 KB total)

  // Chunked bijective XCD swizzle (gridDim.x % 8 == 0): XCD c owns lids
  // [c*q, (c+1)*q). lid = mtile*2 + ct -> both ct siblings AND consecutive
  // same-relation m-tiles live in one XCD chunk -> Xs/W stay L2-resident.
  const int q = gridDim.x >> 3;
  const int lid = ((int)blockIdx.x & 7) * q + ((int)blockIdx.x >> 3);
  const int info = tinfo[lid >> 1];
  if (info < 0) return;
  const int r = info >> 16;
  const int mt = info & 0xFFFF;
  const int ct = lid & 1;
  const int prow0 = pbase[r] + mt * BM;

  const int tid = threadIdx.x;
  const int lane = tid & 63;
  const int wid = tid >> 6;
  const int wr = wid >> 2;          // 0..1 : 64-row band
  const int wc = wid & 3;           // 0..3 : 64-col band
  const int lrow = lane & 15;
  const int gl = lane >> 4;         // k-granule 0..3

  // Staging: row = tid>>2 (128 rows / shot), phys granule tid&3 holds
  // logical (tid&3)^((row>>1)&3) = (tid&3)^((tid>>3)&3).
  const int srow = tid >> 2;
  const int lg = (tid & 3) ^ ((tid >> 3) & 3);
  const unsigned short* asrc = Xs + (size_t)(prow0 + srow) * EMB + lg * 8;
  const unsigned short* bsrc0 =
      Ws + ((size_t)r * EMB + (size_t)(ct * BN + srow)) * EMB + lg * 8;
  const unsigned short* bsrc1 = bsrc0 + (size_t)128 * EMB;

  f32x4 acc[4][4];
  const f32x4 vzero = {0.f, 0.f, 0.f, 0.f};
  #pragma unroll
  for (int m = 0; m < 4; ++m)
    #pragma unroll
    for (int nn = 0; nn < 4; ++nn) acc[m][nn] = vzero;

  STAGE(0, 0);
  STAGE(1, 1);

  ITER(0, 6)   ITER(1, 6)   ITER(2, 6)   ITER(3, 6)
  ITER(4, 6)   ITER(5, 6)   ITER(6, 6)   ITER(7, 6)
  ITER(8, 6)   ITER(9, 6)   ITER(10, 6)  ITER(11, 6)
  ITER(12, 6)  ITER(13, 6)  ITER(14, 3)  ITER(15, 0)

  // Epilogue: D mapping col=lane&15, row=(lane>>4)*4+reg
  #pragma unroll
  for (int m = 0; m < 4; ++m) {
    const int base = prow0 + wr * 64 + m * 16 + gl * 4;
    #pragma unroll
    for (int rg = 0; rg < 4; ++rg) {
      const int tok = ptok[base + rg];
      if (tok >= 0) {
        float* orow = out + (size_t)tok * EMB + ct * BN + wc * 64;
        #pragma unroll
        for (int nn = 0; nn < 4; ++nn)
          orow[nn * 16 + lrow] = acc[m][nn][rg];
      }
    }
  }
}

// Safety-net naive kernel (only if ws too small).
__global__ void naive_kernel(const float* __restrict__ X, const int* __restrict__ rel,
                             const float* __restrict__ W, float* __restrict__ out, int n) {
  int i = blockIdx.x;
  if (i >= n) return;
  int r = rel[i];
  const float* x = X + (size_t)i * EMB;
  const float* Wr = W + (size_t)r * EMB * EMB;
  for (int j = threadIdx.x; j < EMB; j += blockDim.x) {
    const float* w = Wr + (size_t)j * EMB;
    float s = 0.f;
    for (int k = 0; k < EMB; ++k) s += w[k] * x[k];
    out[(size_t)i * EMB + j] = s;
  }
}

extern "C" void kernel_launch(void* const* d_in, const int* in_sizes, int n_in,
                              void* d_out, int out_size, void* d_ws, size_t ws_size,
                              hipStream_t stream) {
  const float* X  = (const float*)d_in[0];
  const int* rel  = (const int*)d_in[1];
  const float* W  = (const float*)d_in[2];
  float* out      = (float*)d_out;
  const int n = in_sizes[1];
  const int welems = in_sizes[2];                 // n_rel * EMB * EMB
  const int padn = n + N_RELC * BM;
  const int maxt = (n + BM - 1) / BM + N_RELC;
  const int maxtp = ((maxt + 3) / 4) * 4;         // grid = 2*maxtp -> %8==0

  const size_t ints = (size_t)64 + n + padn + maxtp;
  const size_t offW = ((ints * sizeof(int) + 255) / 256) * 256;
  const size_t offX = offW + (((size_t)welems * 2 + 255) / 256) * 256;
  const size_t need = offX + (size_t)padn * EMB * 2;

  if (ws_size < need) {
    naive_kernel<<<n, 256, 0, stream>>>(X, rel, W, out, n);
    return;
  }

  int* cnt   = (int*)d_ws;       // 16 (+pad to 64)
  int* pbase = cnt + 16;         // 17
  int* pos   = cnt + 64;         // n
  int* ptok  = pos + n;          // padn
  int* tinfo = ptok + padn;      // maxtp
  unsigned short* Ws = (unsigned short*)((char*)d_ws + offW);
  unsigned short* Xs = (unsigned short*)((char*)d_ws + offX);

  const int gb = (n + 3) / 4;                       // gather blocks
  const int wb = (welems / 8 + 255) / 256;          // convert-W blocks

  hipMemsetAsync(cnt, 0, 64 * sizeof(int), stream);
  histo_rank_fill<<<(padn + 255) / 256, 256, 0, stream>>>(rel, cnt, pos, ptok, n, padn);
  prefix_tiles64<<<1, 64, 0, stream>>>(cnt, pbase, tinfo, maxtp);
  prep_all<<<gb + N_RELC + wb, 256, 0, stream>>>(X, W, rel, pos, pbase, cnt,
                                                 Xs, Ws, ptok, n, welems, gb);

  gg12<<<2 * maxtp, 512, 0, stream>>>(Xs, Ws, pbase, tinfo, ptok, out);
}

// Round 13
// 65.403 us; speedup vs baseline: 1.1784x; 1.0808x over previous
//
#include <hip/hip_runtime.h>
#include <stdint.h>

// RelationTransform: out[i] = W[relation[i]] @ node_emb[i]
// N=32768, EMB=512, 16 relations, fp32 in/out.
// Prepass: histogram sort (ptok) + convert W->bf16 Ws only.
// GEMM gg13 = gg12 core (128x256, 512thr, ring-3, counted vmcnt, verified
// 0-conflict granule swizzle, ct-minor chunked XCD lids) + A-side fused:
// fp32 X rows reg-loaded (ptok gather) one iter early, cvt->bf16, swizzled
// ds_write_b128 into the same As layout. B unchanged (gload_lds from Ws).

#define EMB 512
#define N_RELC 16
#define BM 128
#define BN 256
#define BK 32
#define NKT 16

typedef __attribute__((ext_vector_type(4))) float f32x4;
typedef __attribute__((ext_vector_type(8))) short bf16x8;

__device__ __forceinline__ unsigned short f2bf(float f) {
  unsigned int u = __float_as_uint(f);
  u += 0x7FFFu + ((u >> 16) & 1u);   // round-to-nearest-even
  return (unsigned short)(u >> 16);
}

__device__ __forceinline__ bf16x8 cvt8(f32x4 lo, f32x4 hi) {
  bf16x8 o;
  o[0] = (short)f2bf(lo[0]); o[1] = (short)f2bf(lo[1]);
  o[2] = (short)f2bf(lo[2]); o[3] = (short)f2bf(lo[3]);
  o[4] = (short)f2bf(hi[0]); o[5] = (short)f2bf(hi[1]);
  o[6] = (short)f2bf(hi[2]); o[7] = (short)f2bf(hi[3]);
  return o;
}

__device__ __forceinline__ void gload_lds16(const void* g, void* l) {
  __builtin_amdgcn_global_load_lds(
      (const __attribute__((address_space(1))) unsigned int*)(uintptr_t)g,
      (__attribute__((address_space(3))) unsigned int*)(uintptr_t)l, 16, 0, 0);
}

__global__ void init_counts(int* cnt) {
  if (threadIdx.x < 32) cnt[threadIdx.x] = 0;
}

// Per-block LDS histogram rank; also fills ptok[0..padn) with -1.
__global__ __launch_bounds__(256) void histo_rank_fill(
    const int* __restrict__ rel, int* cnt, int* pos, int* ptok,
    int n, int padn) {
  __shared__ int lcnt[N_RELC];
  __shared__ int lbase[N_RELC];
  const int tid = threadIdx.x;
  if (tid < N_RELC) lcnt[tid] = 0;
  __syncthreads();
  const int i = blockIdx.x * blockDim.x + tid;
  if (i < padn) ptok[i] = -1;
  int r = 0, myrank = 0;
  if (i < n) { r = rel[i]; myrank = atomicAdd(&lcnt[r], 1); }
  __syncthreads();
  if (tid < N_RELC) lbase[tid] = atomicAdd(&cnt[tid], lcnt[tid]);
  __syncthreads();
  if (i < n) pos[i] = lbase[r] + myrank;
}

// Padded segment bases + tile table (1 block, 64 threads).
__global__ void prefix_tiles64(const int* __restrict__ cnt, int* pbase,
                               int* tinfo, int maxt) {
  __shared__ int sb[N_RELC + 1];
  __shared__ int st[N_RELC + 1];
  if (threadIdx.x == 0) {
    int acc = 0, t = 0;
    for (int r = 0; r < N_RELC; ++r) {
      sb[r] = acc; st[r] = t;
      const int nt = (cnt[r] + BM - 1) / BM;
      acc += nt * BM;
      t += nt;
    }
    sb[N_RELC] = acc; st[N_RELC] = t;
  }
  __syncthreads();
  for (int i = threadIdx.x; i <= N_RELC; i += blockDim.x) pbase[i] = sb[i];
  for (int x = threadIdx.x; x < maxt; x += blockDim.x) {
    int v = -1;
    #pragma unroll
    for (int r = 0; r < N_RELC; ++r)
      if (x >= st[r] && x < st[r + 1]) v = (r << 16) | (x - st[r]);
    tinfo[x] = v;
  }
}

__global__ __launch_bounds__(256) void scatter_ptok(
    const int* __restrict__ rel, const int* __restrict__ pos,
    const int* __restrict__ pbase, int* __restrict__ ptok, int n) {
  const int i = blockIdx.x * blockDim.x + threadIdx.x;
  if (i < n) ptok[pbase[rel[i]] + pos[i]] = i;
}

__global__ __launch_bounds__(256) void convert_W(const float* __restrict__ W,
                                                 unsigned short* __restrict__ Ws,
                                                 int welems) {
  const size_t i = ((size_t)blockIdx.x * 256 + threadIdx.x) * 8;
  if (i >= (size_t)welems) return;
  f32x4 a = *reinterpret_cast<const f32x4*>(W + i);
  f32x4 c = *reinterpret_cast<const f32x4*>(W + i + 4);
  bf16x8 o;
  o[0] = f2bf(a[0]); o[1] = f2bf(a[1]); o[2] = f2bf(a[2]); o[3] = f2bf(a[3]);
  o[4] = f2bf(c[0]); o[5] = f2bf(c[1]); o[6] = f2bf(c[2]); o[7] = f2bf(c[3]);
  *reinterpret_cast<bf16x8*>(Ws + i) = o;
}

// ---------------------------------------------------------------------------
// gg13. LDS ring-3: As [128][32] bf16 8KB (rows 64B = 4 granules, phys =
// log ^ ((row>>1)&3)); Bs [256][32] bf16 16KB (same swizzle). 72KB total.
// A path (fused): thread owns row srow=tid>>2, logical granule lg=tid&3.
//   tile k regs loaded at iter k-2 (2x dwordx4 fp32), written (cvt +
//   swizzled ds_write_b128) at iter k-1, computed at iter k.
// B path: 2x gload_lds per slab from Ws (linear dest, source-swizzled col).
// ITER(t): ALOAD(t+2) ; BSTAGE(t+2) ; vmcnt(8) [B slab t landed; 8 newer =
// A(t+1)2 B(t+1)2 A(t+2)2 B(t+2)2] ; barrier ; AWRITE(t+1) ; COMPUTE(t) ;
// lgkm(0) ; barrier.  Tail vmcnt 4 -> 0.
// ---------------------------------------------------------------------------

#define ALOAD(P, KT)                                                           \
  {                                                                            \
    const float* ap_ = aptr + (KT) * BK;                                       \
    a##P##0 = *reinterpret_cast<const f32x4*>(ap_);                            \
    a##P##1 = *reinterpret_cast<const f32x4*>(ap_ + 4);                        \
  }

#define AWRITE(S, P)                                                           \
  {                                                                            \
    bf16x8 w_ = cvt8(a##P##0, a##P##1);                                        \
    *reinterpret_cast<bf16x8*>((char*)&As[S][0] + awoff) = w_;                 \
  }

#define BSTAGE(S, KT)                                                          \
  {                                                                            \
    const int kb_ = (KT) * BK;                                                 \
    gload_lds16(bsrc0 + kb_, (char*)&Bs[S][0] + tid * 16);                     \
    gload_lds16(bsrc1 + kb_, (char*)&Bs[S][0] + 8192 + tid * 16);              \
  }

#define COMPUTE(S)                                                             \
  {                                                                            \
    bf16x8 af[4], bfr[4];                                                      \
    _Pragma("unroll")                                                          \
    for (int m = 0; m < 4; ++m) {                                              \
      const int rr_ = wr * 64 + m * 16 + lrow;                                 \
      af[m] = *reinterpret_cast<const bf16x8*>(                                \
          (const char*)&As[S][0] + rr_ * 64 + ((gl ^ ((rr_ >> 1) & 3)) * 16)); \
    }                                                                          \
    _Pragma("unroll")                                                          \
    for (int nn = 0; nn < 4; ++nn) {                                           \
      const int rw_ = wc * 64 + nn * 16 + lrow;                                \
      bfr[nn] = *reinterpret_cast<const bf16x8*>(                              \
          (const char*)&Bs[S][0] + rw_ * 64 + ((gl ^ ((rw_ >> 1) & 3)) * 16)); \
    }                                                                          \
    __builtin_amdgcn_s_setprio(1);                                             \
    _Pragma("unroll")                                                          \
    for (int m = 0; m < 4; ++m)                                                \
      _Pragma("unroll")                                                        \
      for (int nn = 0; nn < 4; ++nn)                                           \
        acc[m][nn] = __builtin_amdgcn_mfma_f32_16x16x32_bf16(                  \
            af[m], bfr[nn], acc[m][nn], 0, 0, 0);                              \
    __builtin_amdgcn_s_setprio(0);                                             \
  }

#define ITER(T, VM)                                                            \
  {                                                                            \
    if ((T) + 2 < NKT) {                                                       \
      if (((T) & 1) == 0) ALOAD(e, (T) + 2) else ALOAD(o, (T) + 2)             \
      __builtin_amdgcn_sched_barrier(0);                                       \
      BSTAGE(((T) + 2) % 3, (T) + 2);                                          \
      __builtin_amdgcn_sched_barrier(0);                                       \
    }                                                                          \
    asm volatile("s_waitcnt vmcnt(" #VM ")" ::: "memory");                     \
    __builtin_amdgcn_s_barrier();                                              \
    __builtin_amdgcn_sched_barrier(0);                                         \
    if ((T) + 1 < NKT) {                                                       \
      if ((((T) + 1) & 1) == 0) AWRITE(((T) + 1) % 3, e)                       \
      else                      AWRITE(((T) + 1) % 3, o)                       \
    }                                                                          \
    COMPUTE((T) % 3);                                                          \
    asm volatile("s_waitcnt lgkmcnt(0)" ::: "memory");                         \
    __builtin_amdgcn_s_barrier();                                              \
    __builtin_amdgcn_sched_barrier(0);                                         \
  }

__global__ __launch_bounds__(512, 4) void gg13(
    const float* __restrict__ X, const unsigned short* __restrict__ Ws,
    const int* __restrict__ pbase, const int* __restrict__ tinfo,
    const int* __restrict__ ptok, float* __restrict__ out)
{
  __shared__ unsigned short As[3][BM * BK];   // 3 x 8 KB
  __shared__ unsigned short Bs[3][BN * BK];   // 3 x 16 KB  (72 KB total)

  // Chunked bijective XCD swizzle (gridDim.x % 8 == 0); lid = mtile*2 + ct.
  const int q = gridDim.x >> 3;
  const int lid = ((int)blockIdx.x & 7) * q + ((int)blockIdx.x >> 3);
  const int info = tinfo[lid >> 1];
  if (info < 0) return;
  const int r = info >> 16;
  const int mt = info & 0xFFFF;
  const int ct = lid & 1;
  const int prow0 = pbase[r] + mt * BM;

  const int tid = threadIdx.x;
  const int lane = tid & 63;
  const int wid = tid >> 6;
  const int wr = wid >> 2;          // 0..1 : 64-row band
  const int wc = wid & 3;           // 0..3 : 64-col band
  const int lrow = lane & 15;
  const int gl = lane >> 4;         // k-granule 0..3

  // A (fused): thread -> row srow, logical granule lg; swizzled LDS offset.
  const int srow = tid >> 2;
  const int lg = tid & 3;
  const int awoff = srow * 64 + ((lg ^ ((srow >> 1) & 3)) * 16);
  int tokA = ptok[prow0 + srow];
  if (tokA < 0) tokA = 0;           // pad rows read token 0 (discarded)
  const float* aptr = X + (size_t)tokA * EMB + lg * 8;

  // B: linear dest, inverse-swizzled source granule (gg12-verified).
  const int blg = (tid & 3) ^ ((tid >> 3) & 3);
  const unsigned short* bsrc0 =
      Ws + ((size_t)r * EMB + (size_t)(ct * BN + srow)) * EMB + blg * 8;
  const unsigned short* bsrc1 = bsrc0 + (size_t)128 * EMB;

  f32x4 acc[4][4];
  const f32x4 vzero = {0.f, 0.f, 0.f, 0.f};
  #pragma unroll
  for (int m = 0; m < 4; ++m)
    #pragma unroll
    for (int nn = 0; nn < 4; ++nn) acc[m][nn] = vzero;

  f32x4 ae0, ae1, ao0, ao1;

  // Prologue: tiles 0,1 in flight (A regs + B slabs), slab0 A written.
  ALOAD(e, 0)
  __builtin_amdgcn_sched_barrier(0);
  BSTAGE(0, 0);
  __builtin_amdgcn_sched_barrier(0);
  ALOAD(o, 1)
  __builtin_amdgcn_sched_barrier(0);
  BSTAGE(1, 1);
  __builtin_amdgcn_sched_barrier(0);
  AWRITE(0, e)                      // compiler reg-dep waits tile-0 A loads

  ITER(0, 8)   ITER(1, 8)   ITER(2, 8)   ITER(3, 8)
  ITER(4, 8)   ITER(5, 8)   ITER(6, 8)   ITER(7, 8)
  ITER(8, 8)   ITER(9, 8)   ITER(10, 8)  ITER(11, 8)
  ITER(12, 8)  ITER(13, 8)  ITER(14, 4)  ITER(15, 0)

  // Epilogue: D mapping col=lane&15, row=(lane>>4)*4+reg
  #pragma unroll
  for (int m = 0; m < 4; ++m) {
    const int base = prow0 + wr * 64 + m * 16 + gl * 4;
    #pragma unroll
    for (int rg = 0; rg < 4; ++rg) {
      const int tok = ptok[base + rg];
      if (tok >= 0) {
        float* orow = out + (size_t)tok * EMB + ct * BN + wc * 64;
        #pragma unroll
        for (int nn = 0; nn < 4; ++nn)
          orow[nn * 16 + lrow] = acc[m][nn][rg];
      }
    }
  }
}

// Safety-net naive kernel (only if ws too small).
__global__ void naive_kernel(const float* __restrict__ X, const int* __restrict__ rel,
                             const float* __restrict__ W, float* __restrict__ out, int n) {
  int i = blockIdx.x;
  if (i >= n) return;
  int r = rel[i];
  const float* x = X + (size_t)i * EMB;
  const float* Wr = W + (size_t)r * EMB * EMB;
  for (int j = threadIdx.x; j < EMB; j += blockDim.x) {
    const float* w = Wr + (size_t)j * EMB;
    float s = 0.f;
    for (int k = 0; k < EMB; ++k) s += w[k] * x[k];
    out[(size_t)i * EMB + j] = s;
  }
}

extern "C" void kernel_launch(void* const* d_in, const int* in_sizes, int n_in,
                              void* d_out, int out_size, void* d_ws, size_t ws_size,
                              hipStream_t stream) {
  const float* X  = (const float*)d_in[0];
  const int* rel  = (const int*)d_in[1];
  const float* W  = (const float*)d_in[2];
  float* out      = (float*)d_out;
  const int n = in_sizes[1];
  const int welems = in_sizes[2];                 // n_rel * EMB * EMB
  const int padn = n + N_RELC * BM;
  const int maxt = (n + BM - 1) / BM + N_RELC;
  const int maxtp = ((maxt + 3) / 4) * 4;         // grid = 2*maxtp -> %8==0

  const size_t ints = (size_t)64 + n + padn + maxtp;
  const size_t offW = ((ints * sizeof(int) + 255) / 256) * 256;
  const size_t need = offW + (size_t)welems * 2;

  if (ws_size < need) {
    naive_kernel<<<n, 256, 0, stream>>>(X, rel, W, out, n);
    return;
  }

  int* cnt   = (int*)d_ws;       // 16 (+pad to 64)
  int* pbase = cnt + 16;         // 17
  int* pos   = cnt + 64;         // n
  int* ptok  = pos + n;          // padn
  int* tinfo = ptok + padn;      // maxtp
  unsigned short* Ws = (unsigned short*)((char*)d_ws + offW);

  init_counts<<<1, 32, 0, stream>>>(cnt);
  histo_rank_fill<<<(padn + 255) / 256, 256, 0, stream>>>(rel, cnt, pos, ptok, n, padn);
  prefix_tiles64<<<1, 64, 0, stream>>>(cnt, pbase, tinfo, maxtp);
  scatter_ptok<<<(n + 255) / 256, 256, 0, stream>>>(rel, pos, pbase, ptok, n);
  convert_W<<<(welems / 8 + 255) / 256, 256, 0, stream>>>(W, Ws, welems);

  gg13<<<2 * maxtp, 512, 0, stream>>>(X, Ws, pbase, tinfo, ptok, out);
}